// Round 8
// baseline (139.055 us; speedup 1.0000x reference)
//
#include <hip/hip_runtime.h>

#define KDIM 1024

typedef __attribute__((ext_vector_type(8))) short bf16x8;
typedef __attribute__((ext_vector_type(4))) short short4v;
typedef __attribute__((ext_vector_type(4))) float f32x4;
typedef __attribute__((ext_vector_type(2))) unsigned uint2v;

__device__ __forceinline__ short f2bf(float f) {
    union { float f; unsigned u; } x; x.f = f;
    unsigned r = x.u + 0x7fffu + ((x.u >> 16) & 1u);   // RNE
    return (short)(r >> 16);
}

__device__ __forceinline__ bf16x8 cvt8(f32x4 a, f32x4 b) {
    union { unsigned u[4]; bf16x8 v; } r;
    asm("v_cvt_pk_bf16_f32 %0, %1, %2" : "=v"(r.u[0]) : "v"(a.x), "v"(a.y));
    asm("v_cvt_pk_bf16_f32 %0, %1, %2" : "=v"(r.u[1]) : "v"(a.z), "v"(a.w));
    asm("v_cvt_pk_bf16_f32 %0, %1, %2" : "=v"(r.u[2]) : "v"(b.x), "v"(b.y));
    asm("v_cvt_pk_bf16_f32 %0, %1, %2" : "=v"(r.u[3]) : "v"(b.z), "v"(b.w));
    return r.v;
}

__device__ __forceinline__ void gload16(const void* g, void* l) {
    __builtin_amdgcn_global_load_lds(
        (const __attribute__((address_space(1))) void*)g,
        (__attribute__((address_space(3))) void*)l, 16, 0, 0);
}

#define WAIT_VM(n)  asm volatile("s_waitcnt vmcnt(" #n ")" ::: "memory")
#define BARSYNC() do { asm volatile("s_waitcnt lgkmcnt(0)" ::: "memory"); \
                       __builtin_amdgcn_s_barrier();                      \
                       asm volatile("" ::: "memory"); } while (0)
#define BARRIER() do { asm volatile("" ::: "memory"); \
                       __builtin_amdgcn_s_barrier();  \
                       asm volatile("" ::: "memory"); } while (0)

// ---------------------------------------------------------------------------
// Decoder GEMM v4: C[m][n] = sum_k A[m][k]*W[n][k] + bias[n]; M=256, K=1024.
// 392 blocks x 512 thr (8 waves: wr=w>>1 m-quarter of 64 rows, wcq=w&1 n-half
// of 64 cols). acc[4][4] per wave, carried over ALL K (C written once).
// Group = K-quarter (256 k). W staging per group: 128 rows x 1 KB fp32 read
// with PLAIN MONOTONE per-lane loads (one instr = full contiguous 1 KB row
// segment -- the pattern fill/m13 prove saturates HBM), converted to bf16
// in-register, ds_write'd XOR-swizzled into [128 rows][512 B] (64 KB,
// double-buffered = 128 KB LDS). Spill-proof: 8-slot f32x4 ring, fully
// unrolled (static indices), <=32 VGPR of staging state, nothing held across
// the group. A-frags: direct global monotone 1 KB loads (x_frag L2-hot,
// 2x duplication -> 1 MB L2/block). One lgkmcnt+barrier per group.
// ---------------------------------------------------------------------------
__launch_bounds__(512, 2)
__global__ void gemm_dec4(const short* __restrict__ A, const float* __restrict__ W,
                          float* __restrict__ C, const float* __restrict__ bias, int N)
{
    __shared__ __align__(1024) char lds[2][65536];   // [buf][128 rows][512 B bf16]

    const int n0 = blockIdx.x * 128;
    const int t = threadIdx.x;
    const int lane = t & 63;
    const int w = t >> 6;        // 0..7
    const int wr = w >> 1;       // m-quarter (64 rows)
    const int wcq = w & 1;       // n-half (64 cols)
    const int cl = lane & 15;
    const int kc = lane >> 4;    // 0..3

    // W load: row j (0..15 per wave), group kq: full 1 KB contiguous segment
    auto wload = [&](int kq, int j) -> f32x4 {
        int rowg = n0 + w * 16 + j;
        rowg = (rowg < N) ? rowg : (N - 1);
        return *(const f32x4*)(W + (size_t)rowg * KDIM + kq * 256 + lane * 4);
    };
    // cvt + swizzled ds_write_b64: granule l (8B) -> chunk c=l>>1, swz c^(row&7)
    auto wstore = [&](int buf, int j, f32x4 v) {
        const int rowL = w * 16 + j;
        unsigned lo, hi;
        asm("v_cvt_pk_bf16_f32 %0, %1, %2" : "=v"(lo) : "v"(v.x), "v"(v.y));
        asm("v_cvt_pk_bf16_f32 %0, %1, %2" : "=v"(hi) : "v"(v.z), "v"(v.w));
        int addr = rowL * 512 + ((((lane >> 1) ^ (rowL & 7))) << 4) + ((lane & 1) << 3);
        uint2v d; d.x = lo; d.y = hi;
        *(uint2v*)(lds[buf] + addr) = d;
    };

    // bias preload (col depends on nf only)
    float bv[4];
    #pragma unroll
    for (int nf = 0; nf < 4; ++nf) {
        int col = n0 + wcq * 64 + nf * 16 + cl;
        bv[nf] = bias[col < N ? col : 0];
    }

    f32x4 acc[4][4];
    #pragma unroll
    for (int i = 0; i < 4; ++i)
        #pragma unroll
        for (int j = 0; j < 4; ++j)
            acc[i][j] = (f32x4){0.f, 0.f, 0.f, 0.f};

    // prologue: stage group 0 into buf 0 (two batches of 8 rows)
    #pragma unroll
    for (int h = 0; h < 2; ++h) {
        f32x4 tmp[8];
        #pragma unroll
        for (int j = 0; j < 8; ++j) tmp[j] = wload(0, h * 8 + j);
        #pragma unroll
        for (int j = 0; j < 8; ++j) wstore(0, h * 8 + j, tmp[j]);
    }
    BARSYNC();

    #pragma unroll
    for (int kq = 0; kq < 4; ++kq) {
        const int buf = kq & 1;
        const char* Bb = lds[buf];
        f32x4 ring[8];
        if (kq < 3) {
            #pragma unroll
            for (int j = 0; j < 8; ++j) ring[j] = wload(kq + 1, j);   // rows 0..7
        }
        #pragma unroll
        for (int kf = 0; kf < 8; ++kf) {
            // staging: store rows 2kf,2kf+1 (loaded >=4 iters ago), refill slots
            if (kq < 3) {
                wstore(buf ^ 1, 2 * kf,     ring[(2 * kf)     & 7]);
                wstore(buf ^ 1, 2 * kf + 1, ring[(2 * kf + 1) & 7]);
                if (kf < 4) {
                    ring[(2 * kf)     & 7] = wload(kq + 1, 2 * kf + 8);
                    ring[(2 * kf + 1) & 7] = wload(kq + 1, 2 * kf + 9);
                }
            }
            // compute: 4 A global loads + 4 B ds_reads + 16 MFMA
            const int kfg = kq * 8 + kf;
            bf16x8 a[4], b[4];
            #pragma unroll
            for (int mf = 0; mf < 4; ++mf)
                a[mf] = *(const bf16x8*)(A + (size_t)(((wr * 4 + mf) * 32 + kfg) * 64 + lane) * 8);
            #pragma unroll
            for (int nf = 0; nf < 4; ++nf) {
                int row = wcq * 64 + nf * 16 + cl;
                int c = kf * 4 + kc;
                b[nf] = *(const bf16x8*)(Bb + row * 512 + ((c ^ (row & 7)) << 4));
            }
            #pragma unroll
            for (int mf = 0; mf < 4; ++mf)
                #pragma unroll
                for (int nf = 0; nf < 4; ++nf)
                    acc[mf][nf] = __builtin_amdgcn_mfma_f32_16x16x32_bf16(a[mf], b[nf], acc[mf][nf], 0, 0, 0);
        }
        BARSYNC();   // writes of (kq+1) visible; reads of buf done before reuse
    }

    // epilogue: C/D layout col = lane&15, row = (lane>>4)*4 + reg
    #pragma unroll
    for (int mf = 0; mf < 4; ++mf) {
        int row = wr * 64 + mf * 16 + kc * 4;
        #pragma unroll
        for (int nf = 0; nf < 4; ++nf) {
            int col = n0 + wcq * 64 + nf * 16 + cl;
            if (col < N) {
                #pragma unroll
                for (int r = 0; r < 4; ++r)
                    C[(size_t)(row + r) * N + col] = acc[mf][nf][r] + bv[nf];
            }
        }
    }
}

// ---------------------------------------------------------------------------
// GRU gemm (R3 structure, proven; weights L3-resident).
// ---------------------------------------------------------------------------
template<int NF, bool PRED>
__launch_bounds__(256, 2)
__global__ void gemm_pipe(const short* __restrict__ A0, const float* __restrict__ W0,
                          float* __restrict__ C0, int nb0,
                          const short* __restrict__ A1, const float* __restrict__ W1,
                          float* __restrict__ C1,
                          const float* __restrict__ bias, int N, int ldc)
{
    constexpr int WBYTES = NF * 4096;
    constexpr int BUFB   = 16384 + WBYTES;
    __shared__ __align__(1024) char lds[3 * BUFB];

    const int bx = blockIdx.x;
    const short* A; const float* W; float* C; int n0;
    if (bx < nb0) { A = A0; W = W0; C = C0; n0 = bx * (32 * NF); }
    else          { A = A1; W = W1; C = C1; n0 = (bx - nb0) * (32 * NF); }

    const int t = threadIdx.x;
    const int lane = t & 63;
    const int w = t >> 6;
    const int wr = w >> 1;
    const int wc = w & 1;

    const float* gW[NF];
    #pragma unroll
    for (int i = 0; i < NF; ++i) {
        int sl = (i * 4 + w) * 64 + lane;
        int row = sl >> 3, cc = sl & 7;
        int rowg = n0 + row;
        if (PRED) rowg = (rowg < N) ? rowg : (N - 1);
        gW[i] = W + (size_t)rowg * KDIM + ((cc ^ (row & 7)) << 2);
    }
    const short* gA[4];
    #pragma unroll
    for (int j = 0; j < 4; ++j)
        gA[j] = A + (size_t)(j * 4 + w) * 16384 + lane * 8;

    f32x4 acc[8][NF];
    #pragma unroll
    for (int i = 0; i < 8; ++i)
        #pragma unroll
        for (int j = 0; j < NF; ++j)
            acc[i][j] = (f32x4){0.f, 0.f, 0.f, 0.f};

    auto stage = [&](int s, int buf) {
        char* base = lds + buf * BUFB;
        #pragma unroll
        for (int i = 0; i < NF; ++i)
            gload16(gW[i] + s * 32, base + 16384 + (i * 4 + w) * 1024);
        #pragma unroll
        for (int j = 0; j < 4; ++j)
            gload16(gA[j] + s * 512, base + (j * 4 + w) * 1024);
    };

    auto compute = [&](int buf) {
        const char* base = lds + buf * BUFB;
        const char* Wb = base + 16384;
        bf16x8 bfr[NF];
        #pragma unroll
        for (int nf = 0; nf < NF; ++nf) {
            int row = (wc * NF + nf) * 16 + (lane & 15);
            int c0 = (lane >> 4) << 1;
            f32x4 lo = *(const f32x4*)(Wb + row * 128 + ((c0 ^ (row & 7)) << 4));
            f32x4 hi = *(const f32x4*)(Wb + row * 128 + (((c0 + 1) ^ (row & 7)) << 4));
            bfr[nf] = cvt8(lo, hi);
        }
        #pragma unroll
        for (int mf = 0; mf < 8; ++mf) {
            bf16x8 a = *(const bf16x8*)(base + (wr * 8 + mf) * 1024 + lane * 16);
            #pragma unroll
            for (int nf = 0; nf < NF; ++nf)
                acc[mf][nf] = __builtin_amdgcn_mfma_f32_16x16x32_bf16(a, bfr[nf], acc[mf][nf], 0, 0, 0);
        }
    };

    stage(0, 0);
    stage(1, 1);

    int bc = 0, bp = 2;
    for (int s = 0; s < 32; ++s) {
        if (s + 2 < 32) {
            stage(s + 2, bp);
            if constexpr (NF == 2) WAIT_VM(12); else WAIT_VM(10);
        } else if (s + 2 == 32) {
            if constexpr (NF == 2) WAIT_VM(6); else WAIT_VM(5);
        } else {
            WAIT_VM(0);
        }
        BARRIER();
        compute(bc);
        BARRIER();
        bc = (bc == 2) ? 0 : bc + 1;
        bp = (bp == 2) ? 0 : bp + 1;
    }

    #pragma unroll
    for (int mf = 0; mf < 8; ++mf) {
        int row = wr * 128 + mf * 16 + ((lane >> 4) << 2);
        #pragma unroll
        for (int nf = 0; nf < NF; ++nf) {
            int col = n0 + (wc * NF + nf) * 16 + (lane & 15);
            if (PRED && col >= N) continue;
            float bvv = bias ? bias[col] : 0.0f;
            #pragma unroll
            for (int r = 0; r < 4; ++r)
                C[(size_t)(row + r) * ldc + col] = acc[mf][nf][r] + bvv;
        }
    }
}

// Gather embedding row / convert hidden rows into bf16 fragment layout.
__global__ void prep_kernel(const int* __restrict__ ids, const float* __restrict__ hidden,
                            const float* __restrict__ emb,
                            short* __restrict__ x_frag, short* __restrict__ h_frag)
{
    const int m = blockIdx.x;
    const int which = blockIdx.y;
    const int j = threadIdx.x << 3;

    const float* src;
    short* dst;
    if (which == 0) { src = emb + (size_t)ids[m] * KDIM; dst = x_frag; }
    else {
        src = hidden + ((size_t)(which - 1) * 256 + m) * KDIM;
        dst = h_frag + (size_t)(which - 1) * 256 * KDIM;
    }
    f32x4 v0 = *(const f32x4*)(src + j);
    f32x4 v1 = *(const f32x4*)(src + j + 4);
    int mf = m >> 4, rr = m & 15, kf = j >> 5, g = (j >> 3) & 3;
    short* p = dst + (size_t)((mf * 32 + kf) * 64 + g * 16 + rr) * 8;
    short4v a, b;
    a.x = f2bf(v0.x); a.y = f2bf(v0.y); a.z = f2bf(v0.z); a.w = f2bf(v0.w);
    b.x = f2bf(v1.x); b.y = f2bf(v1.y); b.z = f2bf(v1.z); b.w = f2bf(v1.w);
    *(short4v*)p = a;
    *(short4v*)(p + 4) = b;
}

// GRU gates: h_new = (1-z)*n + z*h ; writes fp32 hidden_out and bf16 x fragments.
__global__ void gate_kernel(const float* __restrict__ gi, const float* __restrict__ gh,
                            const float* __restrict__ bi, const float* __restrict__ bh,
                            const float* __restrict__ hprev, float* __restrict__ hout,
                            short* __restrict__ x_frag)
{
    const int m = blockIdx.x;
    const int j = threadIdx.x << 3;
    const float* gim = gi + (size_t)m * 3072;
    const float* ghm = gh + (size_t)m * 3072;
    const float* hp = hprev + (size_t)m * KDIM;
    float* ho = hout + (size_t)m * KDIM;
    int mf = m >> 4, rr = m & 15, kf = j >> 5, g = (j >> 3) & 3;
    short* xp = x_frag + (size_t)((mf * 32 + kf) * 64 + g * 16 + rr) * 8;

    #pragma unroll
    for (int half = 0; half < 2; ++half) {
        int jj = j + half * 4;
        f32x4 vir = *(const f32x4*)(gim + jj);
        f32x4 viz = *(const f32x4*)(gim + 1024 + jj);
        f32x4 vin = *(const f32x4*)(gim + 2048 + jj);
        f32x4 vhr = *(const f32x4*)(ghm + jj);
        f32x4 vhz = *(const f32x4*)(ghm + 1024 + jj);
        f32x4 vhn = *(const f32x4*)(ghm + 2048 + jj);
        f32x4 bir = *(const f32x4*)(bi + jj);
        f32x4 biz = *(const f32x4*)(bi + 1024 + jj);
        f32x4 bin = *(const f32x4*)(bi + 2048 + jj);
        f32x4 bhr = *(const f32x4*)(bh + jj);
        f32x4 bhz = *(const f32x4*)(bh + 1024 + jj);
        f32x4 bhn = *(const f32x4*)(bh + 2048 + jj);
        f32x4 vh  = *(const f32x4*)(hp + jj);
        f32x4 outv;
        short4v xb;
        #pragma unroll
        for (int e = 0; e < 4; ++e) {
            float r = 1.f / (1.f + __expf(-(vir[e] + bir[e] + vhr[e] + bhr[e])));
            float z = 1.f / (1.f + __expf(-(viz[e] + biz[e] + vhz[e] + bhz[e])));
            float n = tanhf(vin[e] + bin[e] + r * (vhn[e] + bhn[e]));
            outv[e] = (1.f - z) * n + z * vh[e];
        }
        *(f32x4*)(ho + jj) = outv;
        xb.x = f2bf(outv[0]); xb.y = f2bf(outv[1]); xb.z = f2bf(outv[2]); xb.w = f2bf(outv[3]);
        *(short4v*)(xp + half * 4) = xb;
    }
}

extern "C" void kernel_launch(void* const* d_in, const int* in_sizes, int n_in,
                              void* d_out, int out_size, void* d_ws, size_t ws_size,
                              hipStream_t stream)
{
    const int*   ids    = (const int*)d_in[0];
    const float* hidden = (const float*)d_in[1];
    const float* emb    = (const float*)d_in[2];
    const float* w_ih   = (const float*)d_in[3];
    const float* w_hh   = (const float*)d_in[4];
    const float* b_ih   = (const float*)d_in[5];
    const float* b_hh   = (const float*)d_in[6];
    const float* dec_w  = (const float*)d_in[7];
    const float* dec_b  = (const float*)d_in[8];

    float* out = (float*)d_out;
    float* logits = out;                                  // [256][50000]
    float* hidden_out = out + (size_t)256 * 50000;        // [2][256][1024]

    short* x_frag = (short*)d_ws;                         // 256*1024 bf16
    short* h_frag = x_frag + 256 * 1024;                  // 2*256*1024 bf16
    float* gi = logits;                                   // scratch in logits region
    float* gh = logits + (size_t)256 * 3072;

    prep_kernel<<<dim3(256, 3), 128, 0, stream>>>(ids, hidden, emb, x_frag, h_frag);

    for (int l = 0; l < 2; ++l) {
        gemm_pipe<1, false><<<192, 256, 0, stream>>>(
            x_frag, w_ih + (size_t)l * 3072 * 1024, gi, 96,
            h_frag + (size_t)l * 256 * 1024, w_hh + (size_t)l * 3072 * 1024, gh,
            nullptr, 3072, 3072);
        gate_kernel<<<256, 128, 0, stream>>>(
            gi, gh, b_ih + (size_t)l * 3072, b_hh + (size_t)l * 3072,
            hidden + (size_t)l * 256 * 1024,
            hidden_out + (size_t)l * 256 * 1024, x_frag);
    }

    // decoder: monotone plain-load W streaming, bf16 LDS, K-slice groups
    gemm_dec4<<<392, 512, 0, stream>>>(x_frag, dec_w, logits, dec_b, 50000);
}